// Round 2
// baseline (3827.481 us; speedup 1.0000x reference)
//
#include <hip/hip_runtime.h>

// Seq2Seq (LSTM enc/dec + attention) for MI355X gfx950.
// Strategy:
//  - batch all non-recurrent GEMMs (input projections, energy, output proj)
//  - bf16 hi/lo split-precision MFMA (3-product) for accuracy-critical GEMMs
//  - per-step kernels for the 111-step recurrence (round 1; persistent later)

using u16 = unsigned short;
using u32 = unsigned int;
using bf16x8 = __attribute__((ext_vector_type(8))) __bf16;
using f32x4  = __attribute__((ext_vector_type(4))) float;
using u32x4  = __attribute__((ext_vector_type(4))) unsigned int;
using u32x2  = __attribute__((ext_vector_type(2))) unsigned int;

__device__ __forceinline__ u16 f2bf(float x) {
  u32 u = __float_as_uint(x);
  u32 r = (u + 0x7FFFu + ((u >> 16) & 1u)) >> 16;  // RNE
  return (u16)r;
}
__device__ __forceinline__ float bf2f(u16 b) { return __uint_as_float(((u32)b) << 16); }
// accurate sigmoid for the recurrent path (111 sequential steps)
__device__ __forceinline__ float sigm(float x) { return 1.f / (1.f + expf(-x)); }

__device__ __forceinline__ f32x4 mfma16(u32x4 a, u32x4 b, f32x4 c) {
  return __builtin_amdgcn_mfma_f32_16x16x32_bf16(
      __builtin_bit_cast(bf16x8, a), __builtin_bit_cast(bf16x8, b), c, 0, 0, 0);
}

// ---------------- transpose + bf16 hi/lo split: T[n][koff+k] = W[k][n] ----------
__global__ __launch_bounds__(256)
void k_transpose_split(const float* __restrict__ W, int K, int N,
                       u16* __restrict__ Thi, u16* __restrict__ Tlo,
                       int ldT, int koff)
{
  __shared__ float tile[32][33];
  const int k0 = blockIdx.y << 5, n0 = blockIdx.x << 5;
  const int tx = threadIdx.x & 31, ty = threadIdx.x >> 5;
  #pragma unroll
  for (int i = ty; i < 32; i += 8)
    tile[i][tx] = W[(size_t)(k0 + i) * N + n0 + tx];
  __syncthreads();
  #pragma unroll
  for (int i = ty; i < 32; i += 8) {
    float v = tile[tx][i];
    u16 hi = f2bf(v);
    size_t di = (size_t)(n0 + i) * ldT + koff + k0 + tx;
    Thi[di] = hi;
    if (Tlo) Tlo[di] = f2bf(v - bf2f(hi));
  }
}

// ---------------- embedding gather -> bf16 rows (row = t*32 + n) ----------------
__global__ __launch_bounds__(256)
void k_embed(const float* __restrict__ emb, const int* __restrict__ toks,
             int tokStride, int nRows, u16* __restrict__ A)
{
  int id = blockIdx.x * 256 + threadIdx.x;  // one thread per 8 elements
  if (id >= nRows * 64) return;
  int r = id >> 6, c8 = (id & 63) << 3;
  int t = r >> 5, n = r & 31;
  int tok = toks[n * tokStride + t];
  const float* s = emb + (size_t)tok * 512 + c8;
  f32x4 x0 = *(const f32x4*)s;
  f32x4 x1 = *(const f32x4*)(s + 4);
  u32x4 w;
  w[0] = (u32)f2bf(x0[0]) | ((u32)f2bf(x0[1]) << 16);
  w[1] = (u32)f2bf(x0[2]) | ((u32)f2bf(x0[3]) << 16);
  w[2] = (u32)f2bf(x1[0]) | ((u32)f2bf(x1[1]) << 16);
  w[3] = (u32)f2bf(x1[2]) | ((u32)f2bf(x1[3]) << 16);
  *(u32x4*)(A + (size_t)r * 512 + c8) = w;
}

// ---------------- batch GEMM: C[M][N] = A[M][K] * BT[N][K]^T + bias -------------
// X2: 3-product bf16 hi/lo split (~fp32 accuracy). OUTMAP: remap row t*32+n -> n*47+t.
// Fragment note: A and B fragments are loaded with the IDENTICAL lane->(row,kset)
// addressing, so any intra-instruction K-permutation cancels; C/D layout is the
// m89-verified col=lane&15, row=(lane>>4)*4+reg.
template<bool X2, int OUTMAP>
__global__ __launch_bounds__(256)
void gemm_k(const u16* __restrict__ Ah, const u16* __restrict__ Al,
            const u16* __restrict__ Bh, const u16* __restrict__ Bl,
            const float* __restrict__ bias, float* __restrict__ C,
            int M, int N, int K, int Mstore)
{
  const int lane = threadIdx.x & 63, wave = threadIdx.x >> 6;
  const int m0 = blockIdx.y * 128 + (wave >> 1) * 64;
  const int n0 = blockIdx.x * 128 + (wave & 1) * 64;
  const int fr = lane & 15, fq = lane >> 4;
  const f32x4 z = {0.f, 0.f, 0.f, 0.f};
  f32x4 acc[4][4];
  #pragma unroll
  for (int i = 0; i < 4; i++)
    #pragma unroll
    for (int j = 0; j < 4; j++) acc[i][j] = z;

  const size_t a_base = (size_t)(m0 + fr) * K + fq * 8;
  const size_t b_base = (size_t)(n0 + fr) * K + fq * 8;
  for (int k0 = 0; k0 < K; k0 += 32) {
    u32x4 a[4], b[4], a2[4], b2[4];
    #pragma unroll
    for (int i = 0; i < 4; i++) a[i] = *(const u32x4*)(Ah + a_base + (size_t)i * 16 * K + k0);
    #pragma unroll
    for (int j = 0; j < 4; j++) b[j] = *(const u32x4*)(Bh + b_base + (size_t)j * 16 * K + k0);
    if constexpr (X2) {
      #pragma unroll
      for (int i = 0; i < 4; i++) a2[i] = *(const u32x4*)(Al + a_base + (size_t)i * 16 * K + k0);
      #pragma unroll
      for (int j = 0; j < 4; j++) b2[j] = *(const u32x4*)(Bl + b_base + (size_t)j * 16 * K + k0);
    }
    #pragma unroll
    for (int i = 0; i < 4; i++)
      #pragma unroll
      for (int j = 0; j < 4; j++) {
        acc[i][j] = mfma16(a[i], b[j], acc[i][j]);
        if constexpr (X2) {
          acc[i][j] = mfma16(a[i], b2[j], acc[i][j]);
          acc[i][j] = mfma16(a2[i], b[j], acc[i][j]);
        }
      }
  }
  #pragma unroll
  for (int i = 0; i < 4; i++) {
    int row_b = m0 + i * 16 + fq * 4;  // C/D: row=(lane>>4)*4+r, col=lane&15
    #pragma unroll
    for (int j = 0; j < 4; j++) {
      int col = n0 + j * 16 + fr;
      float bv = bias ? bias[col] : 0.f;
      #pragma unroll
      for (int r = 0; r < 4; r++) {
        int row = row_b + r;
        if (row < Mstore) {
          float v = acc[i][j][r] + bv;
          if (OUTMAP) {
            int nn = row & 31, tt = row >> 5;
            C[(size_t)(nn * 47 + tt) * N + col] = v;
          } else {
            C[(size_t)row * N + col] = v;
          }
        }
      }
    }
  }
}

// ---------------- recurrent GEMM: partial[s][32][4096] = A[32][KK] * BT[4096][KK]^T
// always 3-product hi/lo. grid = (4096/256, SPLITK)
__global__ __launch_bounds__(256)
void rec_gemm(const u16* __restrict__ Ah, const u16* __restrict__ Al,
              const u16* __restrict__ Bh, const u16* __restrict__ Bl,
              float* __restrict__ partial, int KK, int kchunk)
{
  const int lane = threadIdx.x & 63, wave = threadIdx.x >> 6;
  const int n0 = blockIdx.x * 256 + wave * 64;
  const int fr = lane & 15, fq = lane >> 4;
  const int ks = blockIdx.y * kchunk, ke = ks + kchunk;
  const f32x4 z = {0.f, 0.f, 0.f, 0.f};
  f32x4 acc[2][4];
  #pragma unroll
  for (int i = 0; i < 2; i++)
    #pragma unroll
    for (int j = 0; j < 4; j++) acc[i][j] = z;

  for (int k0 = ks; k0 < ke; k0 += 32) {
    u32x4 a[2], a2[2], b[4], b2[4];
    #pragma unroll
    for (int i = 0; i < 2; i++) {
      size_t o = (size_t)(i * 16 + fr) * KK + k0 + fq * 8;
      a[i]  = *(const u32x4*)(Ah + o);
      a2[i] = *(const u32x4*)(Al + o);
    }
    #pragma unroll
    for (int j = 0; j < 4; j++) {
      size_t o = (size_t)(n0 + j * 16 + fr) * KK + k0 + fq * 8;
      b[j]  = *(const u32x4*)(Bh + o);
      b2[j] = *(const u32x4*)(Bl + o);
    }
    #pragma unroll
    for (int i = 0; i < 2; i++)
      #pragma unroll
      for (int j = 0; j < 4; j++) {
        acc[i][j] = mfma16(a[i], b[j], acc[i][j]);
        acc[i][j] = mfma16(a[i], b2[j], acc[i][j]);
        acc[i][j] = mfma16(a2[i], b[j], acc[i][j]);
      }
  }
  float* pb = partial + (size_t)blockIdx.y * 32 * 4096;
  #pragma unroll
  for (int i = 0; i < 2; i++)
    #pragma unroll
    for (int j = 0; j < 4; j++)
      #pragma unroll
      for (int r = 0; r < 4; r++) {
        int row = i * 16 + fq * 4 + r;
        int col = n0 + j * 16 + fr;
        pb[(size_t)row * 4096 + col] = acc[i][j][r];
      }
}

// ---------------- LSTM pointwise (encoder) --------------------------------------
__global__ __launch_bounds__(256)
void point_enc(const float* __restrict__ partial, const float* __restrict__ Xi,
               float* __restrict__ c, float* __restrict__ hf,
               u16* __restrict__ hhi, u16* __restrict__ hlo, int usep)
{
  int idx = blockIdx.x * 256 + threadIdx.x;  // 32*1024
  int n = idx >> 10, hh = idx & 1023;
  size_t xb = (size_t)n * 4096 + hh;
  float g[4];
  #pragma unroll
  for (int j = 0; j < 4; j++) {
    float v = Xi[xb + j * 1024];
    if (usep) {
      #pragma unroll
      for (int s = 0; s < 8; s++) v += partial[(size_t)(s * 32 + n) * 4096 + j * 1024 + hh];
    }
    g[j] = v;
  }
  float cp = usep ? c[idx] : 0.f;
  float cn = sigm(g[1]) * cp + sigm(g[0]) * tanhf(g[2]);
  float hv = sigm(g[3]) * tanhf(cn);
  c[idx] = cn;
  hf[idx] = hv;
  u16 hi = f2bf(hv);
  hhi[idx] = hi;
  hlo[idx] = f2bf(hv - bf2f(hi));
}

// ---------------- LSTM pointwise (decoder) --------------------------------------
__global__ __launch_bounds__(256)
void point_dec(const float* __restrict__ partial, const float* __restrict__ Xi,
               float* __restrict__ c, float* __restrict__ hf,
               u16* __restrict__ xh, u16* __restrict__ xl,
               u16* __restrict__ dh, u16* __restrict__ dl)
{
  int idx = blockIdx.x * 256 + threadIdx.x;
  int n = idx >> 10, hh = idx & 1023;
  size_t xb = (size_t)n * 4096 + hh;
  float g[4];
  #pragma unroll
  for (int j = 0; j < 4; j++) {
    float v = Xi[xb + j * 1024];
    #pragma unroll
    for (int s = 0; s < 8; s++) v += partial[(size_t)(s * 32 + n) * 4096 + j * 1024 + hh];
    g[j] = v;
  }
  float cn = sigm(g[1]) * c[idx] + sigm(g[0]) * tanhf(g[2]);
  float hv = sigm(g[3]) * tanhf(cn);
  c[idx] = cn;
  hf[idx] = hv;
  u16 hi = f2bf(hv);
  u16 lo = f2bf(hv - bf2f(hi));
  size_t xo = (size_t)n * 2048 + 1024 + hh;
  xh[xo] = hi; xl[xo] = lo;
  dh[idx] = hi; dl[idx] = lo;
}

// ---------------- attention: scores->softmax->ctx, ctx -> xcat[:,0:1024] --------
__global__ __launch_bounds__(256)
void attn_k(const float* __restrict__ energy, const float* __restrict__ ench,
            const float* __restrict__ h, const int* __restrict__ src,
            u16* __restrict__ xh, u16* __restrict__ xl)
{
  __shared__ float shh[1024];
  __shared__ float red[256];
  __shared__ float sw[64];
  const int n = blockIdx.x, tid = threadIdx.x;
  ((f32x4*)shh)[tid] = ((const f32x4*)(h + ((size_t)n << 10)))[tid];
  __syncthreads();
  // scores: l = tid>>2 (64 rows), q = tid&3 (K-quarter of 256)
  {
    int l = tid >> 2, q = tid & 3;
    const float* er = energy + (((size_t)(l * 32 + n)) << 10) + q * 256;
    const float* hc = shh + q * 256;
    float p = 0.f;
    #pragma unroll 8
    for (int j = 0; j < 256; j += 4) {
      f32x4 e4 = *(const f32x4*)(er + j);
      p += e4[0] * hc[j] + e4[1] * hc[j + 1] + e4[2] * hc[j + 2] + e4[3] * hc[j + 3];
    }
    red[tid] = p;
  }
  __syncthreads();
  if (tid < 64) {
    float sco = red[tid * 4] + red[tid * 4 + 1] + red[tid * 4 + 2] + red[tid * 4 + 3];
    if (src[n * 64 + tid] == 0) sco = -1e9f;  // PAD mask
    float mm = sco;
    #pragma unroll
    for (int off = 32; off; off >>= 1) mm = fmaxf(mm, __shfl_xor(mm, off));
    float e = __expf(sco - mm), su = e;
    #pragma unroll
    for (int off = 32; off; off >>= 1) su += __shfl_xor(su, off);
    sw[tid] = e / su;
  }
  __syncthreads();
  // ctx: 4 columns per thread
  int c0 = tid * 4;
  float a0 = 0.f, a1 = 0.f, a2 = 0.f, a3 = 0.f;
  for (int l = 0; l < 64; l++) {
    float wl = sw[l];
    const f32x4 v = *(const f32x4*)(ench + (((size_t)(l * 32 + n)) << 10) + c0);
    a0 += wl * v[0]; a1 += wl * v[1]; a2 += wl * v[2]; a3 += wl * v[3];
  }
  u16 h0 = f2bf(a0), h1 = f2bf(a1), h2 = f2bf(a2), h3 = f2bf(a3);
  u16 l0 = f2bf(a0 - bf2f(h0)), l1 = f2bf(a1 - bf2f(h1));
  u16 l2 = f2bf(a2 - bf2f(h2)), l3 = f2bf(a3 - bf2f(h3));
  u32x2 hv, lv;
  hv[0] = (u32)h0 | ((u32)h1 << 16); hv[1] = (u32)h2 | ((u32)h3 << 16);
  lv[0] = (u32)l0 | ((u32)l1 << 16); lv[1] = (u32)l2 | ((u32)l3 << 16);
  *(u32x2*)(xh + (size_t)n * 2048 + c0) = hv;
  *(u32x2*)(xl + (size_t)n * 2048 + c0) = lv;
}

// ---------------- seed decoder xcat h-part from encoder final h -----------------
__global__ __launch_bounds__(256)
void k_prep_xcat(const u16* __restrict__ sh, const u16* __restrict__ sl,
                 u16* __restrict__ xh, u16* __restrict__ xl)
{
  int idx = blockIdx.x * 256 + threadIdx.x;
  int n = idx >> 10, hh = idx & 1023;
  size_t xo = (size_t)n * 2048 + 1024 + hh;
  xh[xo] = sh[idx];
  xl[xo] = sl[idx];
}

// ---------------- in-place log-softmax over 32000-wide rows of d_out ------------
__global__ __launch_bounds__(256)
void k_logsoftmax(float* __restrict__ out)
{
  float* row = out + (size_t)blockIdx.x * 32000;
  const int tid = threadIdx.x;
  float m = -3.0e38f, s = 0.f;
  for (int i = tid; i < 8000; i += 256) {
    f32x4 x = ((const f32x4*)row)[i];
    #pragma unroll
    for (int j = 0; j < 4; j++) {
      float v = x[j];
      if (v > m) { s = s * __expf(m - v) + 1.f; m = v; }
      else s += __expf(v - m);
    }
  }
  #pragma unroll
  for (int off = 32; off; off >>= 1) {
    float m2 = __shfl_xor(m, off), s2 = __shfl_xor(s, off);
    float M = fmaxf(m, m2);
    s = s * __expf(m - M) + s2 * __expf(m2 - M);
    m = M;
  }
  __shared__ float sm[4], ss[4];
  if ((tid & 63) == 0) { sm[tid >> 6] = m; ss[tid >> 6] = s; }
  __syncthreads();
  float M = fmaxf(fmaxf(sm[0], sm[1]), fmaxf(sm[2], sm[3]));
  float S = ss[0] * __expf(sm[0] - M) + ss[1] * __expf(sm[1] - M) +
            ss[2] * __expf(sm[2] - M) + ss[3] * __expf(sm[3] - M);
  float lse = M + __logf(S);
  for (int i = tid; i < 8000; i += 256) {
    f32x4 x = ((f32x4*)row)[i];
    x[0] -= lse; x[1] -= lse; x[2] -= lse; x[3] -= lse;
    ((f32x4*)row)[i] = x;
  }
}

// ================================================================================
extern "C" void kernel_launch(void* const* d_in, const int* in_sizes, int n_in,
                              void* d_out, int out_size, void* d_ws, size_t ws_size,
                              hipStream_t stream)
{
  (void)in_sizes; (void)n_in; (void)out_size; (void)ws_size;
  const int*   src  = (const int*)d_in[0];
  const int*   tgt  = (const int*)d_in[1];
  const float* eemb = (const float*)d_in[2];
  const float* eWi  = (const float*)d_in[3];
  const float* eWh  = (const float*)d_in[4];
  const float* eb   = (const float*)d_in[5];
  const float* demb = (const float*)d_in[6];
  const float* dWi  = (const float*)d_in[7];
  const float* dWh  = (const float*)d_in[8];
  const float* db   = (const float*)d_in[9];
  const float* aW   = (const float*)d_in[10];
  const float* ab   = (const float*)d_in[11];
  const float* hW   = (const float*)d_in[12];
  const float* hb   = (const float*)d_in[13];
  float* out = (float*)d_out;

  char* wsp = (char*)d_ws;
  size_t off = 0;
  auto alloc = [&](size_t bytes) -> void* {
    void* p = wsp + off;
    off += (bytes + 255) & ~(size_t)255;
    return p;
  };
  // bf16 transposed weights
  u16* WiTe  = (u16*)alloc((size_t)4096 * 512 * 2);     // enc_Wi^T (hi)
  u16* WhTh  = (u16*)alloc((size_t)4096 * 1024 * 2);    // enc_Wh^T hi
  u16* WhTl  = (u16*)alloc((size_t)4096 * 1024 * 2);    //          lo
  u16* DWiTe = (u16*)alloc((size_t)4096 * 512 * 2);     // dec_Wi[:512]^T (hi)
  u16* WcTh  = (u16*)alloc((size_t)4096 * 2048 * 2);    // [dec_Wi[512:]; dec_Wh]^T hi
  u16* WcTl  = (u16*)alloc((size_t)4096 * 2048 * 2);    //                         lo
  u16* AwTh  = (u16*)alloc((size_t)1024 * 1024 * 2);    // attn_W^T hi
  u16* AwTl  = (u16*)alloc((size_t)1024 * 1024 * 2);    //          lo
  u16* HoTh  = (u16*)alloc((size_t)32000 * 1024 * 2);   // h2o_W^T hi
  u16* HoTl  = (u16*)alloc((size_t)32000 * 1024 * 2);   //         lo
  // activations
  u16*   Aenc   = (u16*)alloc((size_t)2048 * 512 * 2);
  u16*   Adec   = (u16*)alloc((size_t)1536 * 512 * 2);
  float* XiE    = (float*)alloc((size_t)2048 * 4096 * 4);
  float* XiD    = (float*)alloc((size_t)1536 * 4096 * 4);
  float* ench   = (float*)alloc((size_t)64 * 32 * 1024 * 4);
  u16*   encHh  = (u16*)alloc((size_t)64 * 32 * 1024 * 2);
  u16*   encHl  = (u16*)alloc((size_t)64 * 32 * 1024 * 2);
  float* energy = (float*)alloc((size_t)64 * 32 * 1024 * 4);
  float* cbuf   = (float*)alloc((size_t)32 * 1024 * 4);
  float* hdec   = (float*)alloc((size_t)32 * 1024 * 4);
  u16*   xh     = (u16*)alloc((size_t)32 * 2048 * 2);
  u16*   xl     = (u16*)alloc((size_t)32 * 2048 * 2);
  u16*   dechh  = (u16*)alloc((size_t)1536 * 1024 * 2);
  u16*   dechl  = (u16*)alloc((size_t)1536 * 1024 * 2);
  float* partial = (float*)alloc((size_t)8 * 32 * 4096 * 4);

  dim3 B(256);

  // ---- weight prep ----
  k_transpose_split<<<dim3(128, 16), B, 0, stream>>>(eWi, 512, 4096, WiTe, nullptr, 512, 0);
  k_transpose_split<<<dim3(128, 32), B, 0, stream>>>(eWh, 1024, 4096, WhTh, WhTl, 1024, 0);
  k_transpose_split<<<dim3(128, 16), B, 0, stream>>>(dWi, 512, 4096, DWiTe, nullptr, 512, 0);
  k_transpose_split<<<dim3(128, 32), B, 0, stream>>>(dWi + (size_t)512 * 4096, 1024, 4096, WcTh, WcTl, 2048, 0);
  k_transpose_split<<<dim3(128, 32), B, 0, stream>>>(dWh, 1024, 4096, WcTh, WcTl, 2048, 1024);
  k_transpose_split<<<dim3(32, 32),  B, 0, stream>>>(aW, 1024, 1024, AwTh, AwTl, 1024, 0);
  k_transpose_split<<<dim3(1000, 32), B, 0, stream>>>(hW, 1024, 32000, HoTh, HoTl, 1024, 0);

  // ---- embeddings ----
  k_embed<<<512, B, 0, stream>>>(eemb, src, 64, 2048, Aenc);
  k_embed<<<376, B, 0, stream>>>(demb, tgt, 48, 1504, Adec);

  // ---- batch input projections (single-bf16: inputs ~0.02, error negligible) ----
  gemm_k<false, 0><<<dim3(32, 16), B, 0, stream>>>(Aenc, nullptr, WiTe, nullptr, eb, XiE, 2048, 4096, 512, 2048);
  gemm_k<false, 0><<<dim3(32, 12), B, 0, stream>>>(Adec, nullptr, DWiTe, nullptr, db, XiD, 1536, 4096, 512, 1536);

  // ---- encoder recurrence ----
  for (int t = 0; t < 64; t++) {
    if (t > 0)
      rec_gemm<<<dim3(16, 8), B, 0, stream>>>(encHh + (size_t)(t - 1) * 32768,
                                              encHl + (size_t)(t - 1) * 32768,
                                              WhTh, WhTl, partial, 1024, 128);
    point_enc<<<128, B, 0, stream>>>(partial, XiE + (size_t)t * 131072, cbuf,
                                     ench + (size_t)t * 32768,
                                     encHh + (size_t)t * 32768,
                                     encHl + (size_t)t * 32768, t > 0 ? 1 : 0);
  }

  // ---- energy = enc_h @ attn_W + attn_b (x2 split) ----
  gemm_k<true, 0><<<dim3(8, 16), B, 0, stream>>>(encHh, encHl, AwTh, AwTl, ab, energy, 2048, 1024, 1024, 2048);

  // ---- decoder recurrence ----
  k_prep_xcat<<<128, B, 0, stream>>>(encHh + (size_t)63 * 32768, encHl + (size_t)63 * 32768, xh, xl);
  for (int t = 0; t < 47; t++) {
    const float* hp = (t == 0) ? (ench + (size_t)63 * 32768) : hdec;
    attn_k<<<32, B, 0, stream>>>(energy, ench, hp, src, xh, xl);
    rec_gemm<<<dim3(16, 8), B, 0, stream>>>(xh, xl, WcTh, WcTl, partial, 2048, 256);
    point_dec<<<128, B, 0, stream>>>(partial, XiD + (size_t)t * 131072, cbuf, hdec,
                                     xh, xl,
                                     dechh + (size_t)t * 32768,
                                     dechl + (size_t)t * 32768);
  }

  // ---- output projection (x2 split) directly into d_out ([n][t][v] order) ----
  gemm_k<true, 1><<<dim3(250, 12), B, 0, stream>>>(dechh, dechl, HoTh, HoTl, hb, out, 1536, 32000, 1024, 1504);

  // ---- in-place log-softmax ----
  k_logsoftmax<<<1504, B, 0, stream>>>(out);
}